// Round 2
// baseline (548.025 us; speedup 1.0000x reference)
//
#include <hip/hip_runtime.h>
#include <climits>

#define TOTAL 1000000
#define D     128
#define B     4096
#define W     256

__global__ __launch_bounds__(256) void pool_kernel(
    const float* __restrict__ mu,
    const float* __restrict__ sigma,
    const float* __restrict__ params,
    float* __restrict__ out_agg,
    float* __restrict__ out_start)   // harness reads whole d_out as f32
{
    const int b = blockIdx.x;
    const int t = threadIdx.x;

    __shared__ float  s_w[W];
    __shared__ float  s_wavesum[4];
    __shared__ int    s_lo, s_hi;
    __shared__ float4 s_part[8][32];

    // ---- per-row scalars (match reference exactly) ----
    const float center = mu[b] * 999999.0f;                 // mu * (TOTAL-1)
    float cs = center - 128.0f;                             // - W//2
    cs = fminf(fmaxf(cs, 0.0f), (float)(TOTAL - W));        // clip, then
    const int start = (int)cs;                              // trunc to i32

    const float sg     = sigma[b] + 1e-6f;
    const float inv2s2 = 1.0f / (2.0f * sg * sg);

    // ---- phase 1: weights for all 256 window rows ----
    const float dist = (float)(start + t) - center;
    const float wgt  = __expf(-dist * dist * inv2s2);
    s_w[t] = wgt;
    if (t == 0) { s_lo = INT_MAX; s_hi = -1; }

    // wave64 reduce, then combine 4 waves via LDS
    float v = wgt;
    #pragma unroll
    for (int off = 32; off > 0; off >>= 1) v += __shfl_down(v, off, 64);
    if ((t & 63) == 0) s_wavesum[t >> 6] = v;
    __syncthreads();

    const float sum = s_wavesum[0] + s_wavesum[1] + s_wavesum[2] + s_wavesum[3];
    const float inv = 1.0f / (sum + 1e-6f);

    // active range: rows whose weight matters (Gaussian => contiguous).
    // Skipped rows contribute < 1e-9 relative — far below f32 validation noise.
    if (wgt > 1e-9f * sum) {
        atomicMin(&s_lo, t);
        atomicMax(&s_hi, t);
    }
    __syncthreads();
    const int wlo = s_lo, whi = s_hi;

    // ---- phase 2: weighted accumulation over active rows ----
    const int c = t & 31;   // float4 column group: cols 4c..4c+3
    const int r = t >> 5;   // row group 0..7
    float4 acc = make_float4(0.f, 0.f, 0.f, 0.f);

    if (wlo <= whi) {
        const float4* __restrict__ prow =
            (const float4*)(params + (size_t)start * D);
        for (int w = wlo + r; w <= whi; w += 8) {
            const float4 p  = prow[(size_t)w * 32 + c];
            const float  ww = s_w[w];
            acc.x += ww * p.x; acc.y += ww * p.y;
            acc.z += ww * p.z; acc.w += ww * p.w;
        }
    }
    s_part[r][c] = acc;
    __syncthreads();

    // ---- reduce 8 row-group partials, normalize, store ----
    if (t < 32) {
        float4 a = s_part[0][t];
        #pragma unroll
        for (int rr = 1; rr < 8; ++rr) {
            const float4 p = s_part[rr][t];
            a.x += p.x; a.y += p.y; a.z += p.z; a.w += p.w;
        }
        a.x *= inv; a.y *= inv; a.z *= inv; a.w *= inv;
        ((float4*)(out_agg + (size_t)b * D))[t] = a;
    }
    if (t == 0) out_start[b] = (float)start;   // f32 value, not int bits
}

extern "C" void kernel_launch(void* const* d_in, const int* in_sizes, int n_in,
                              void* d_out, int out_size, void* d_ws, size_t ws_size,
                              hipStream_t stream) {
    const float* mu     = (const float*)d_in[0];
    const float* sigma  = (const float*)d_in[1];
    const float* params = (const float*)d_in[2];

    float* out_agg   = (float*)d_out;                      // B*D floats
    float* out_start = out_agg + (size_t)B * D;            // B floats (start idx)

    pool_kernel<<<B, 256, 0, stream>>>(mu, sigma, params, out_agg, out_start);
}

// Round 3
// 547.118 us; speedup vs baseline: 1.0017x; 1.0017x over previous
//
#include <hip/hip_runtime.h>

#define TOTAL 1000000
#define D     128
#define NB    4096
#define W     256
#define WPB   4   // one wave per b, 4 b's per 256-thread block

__global__ __launch_bounds__(256) void pool_kernel(
    const float* __restrict__ mu,
    const float* __restrict__ sigma,
    const float* __restrict__ params,
    float* __restrict__ out_agg,
    float* __restrict__ out_start)   // harness reads whole d_out as f32
{
    const int t    = threadIdx.x;
    const int wv   = t >> 6;          // wave id within block
    const int lane = t & 63;
    const int b    = blockIdx.x * WPB + wv;

    __shared__ float s_w[WPB][W];     // per-wave weight table (4 KB)

    // ---- per-b scalars (match reference exactly) ----
    const float center = mu[b] * 999999.0f;               // mu * (TOTAL-1)
    const float sg     = sigma[b] + 1e-6f;
    const float cs     = fminf(fmaxf(center - 128.0f, 0.0f), 999744.0f); // clip to [0, TOTAL-W]
    const int   start  = (int)cs;                          // trunc like astype(i32)
    const float inv2s2 = 1.0f / (2.0f * sg * sg);

    // ---- weights: 4 per lane, kept in regs + stashed in LDS for gather ----
    float wr[4];
    #pragma unroll
    for (int k = 0; k < 4; ++k) {
        const float d = (float)(start + lane + 64 * k) - center;
        wr[k] = __expf(-d * d * inv2s2);
        s_w[wv][lane + 64 * k] = wr[k];
    }

    // wave butterfly sum of all 256 weights
    float ws = (wr[0] + wr[1]) + (wr[2] + wr[3]);
    #pragma unroll
    for (int off = 32; off > 0; off >>= 1) ws += __shfl_xor(ws, off, 64);
    const float sum = ws;
    const float inv = 1.0f / (sum + 1e-6f);
    const float thr = 1e-9f * sum;    // rows below this contribute <1e-9 rel.

    // ---- active range via ballots (Gaussian => contiguous) ----
    unsigned long long m[4];
    #pragma unroll
    for (int k = 0; k < 4; ++k) m[k] = __ballot(wr[k] > thr);

    int lo = W, hi = -1;
    #pragma unroll
    for (int k = 3; k >= 0; --k)
        if (m[k]) lo = 64 * k + (__ffsll((unsigned long long)m[k]) - 1);
    #pragma unroll
    for (int k = 0; k < 4; ++k)
        if (m[k]) hi = 64 * k + (63 - __clzll((unsigned long long)m[k]));

    // ---- gather: half-wave per row, float4 per lane ----
    const int half = lane >> 5;       // 0: even rows, 1: odd rows
    const int col  = lane & 31;       // float4 column
    float4 acc = make_float4(0.f, 0.f, 0.f, 0.f);
    const float4* __restrict__ prow = (const float4*)(params + (size_t)start * D);
    for (int j = lo + half; j <= hi; j += 2) {
        const float4 p  = prow[(size_t)j * 32 + col];
        const float  ww = s_w[wv][j];
        acc.x += ww * p.x; acc.y += ww * p.y;
        acc.z += ww * p.z; acc.w += ww * p.w;
    }

    // combine even/odd half-wave partials
    acc.x += __shfl_xor(acc.x, 32, 64);
    acc.y += __shfl_xor(acc.y, 32, 64);
    acc.z += __shfl_xor(acc.z, 32, 64);
    acc.w += __shfl_xor(acc.w, 32, 64);

    if (half == 0) {
        float4 r;
        r.x = acc.x * inv; r.y = acc.y * inv;
        r.z = acc.z * inv; r.w = acc.w * inv;
        ((float4*)(out_agg + (size_t)b * D))[col] = r;
    }
    if (lane == 0) out_start[b] = (float)start;  // f32 value, not int bits
}

extern "C" void kernel_launch(void* const* d_in, const int* in_sizes, int n_in,
                              void* d_out, int out_size, void* d_ws, size_t ws_size,
                              hipStream_t stream) {
    const float* mu     = (const float*)d_in[0];
    const float* sigma  = (const float*)d_in[1];
    const float* params = (const float*)d_in[2];

    float* out_agg   = (float*)d_out;             // NB*D floats
    float* out_start = out_agg + (size_t)NB * D;  // NB floats (start idx values)

    pool_kernel<<<NB / WPB, 256, 0, stream>>>(mu, sigma, params, out_agg, out_start);
}